// Round 11
// baseline (6682.823 us; speedup 1.0000x reference)
//
#include <hip/hip_runtime.h>
#include <math.h>

// Problem constants (reference: BS=32, N=M=1024, eps=0.1, 200 iters)
#define BS    32
#define N     1024
#define M     1024
#define ITERS 200

// R4's proven minimal skeleton, unchanged:
//   8 WGs per batch, 512 threads, grid 256 = 1 WG/CU, 3 intra-WG syncs,
//   one 8-wide atomic inter-WG barrier, flat 8-way v-reduce.
// Delta vs R4: 56 of the 128 rows/WG live in LDS as packed u16 (112 KB);
// 72 rows stream from u16 cq (144 KB/WG/iter, -44% sweep bytes).
// CRITICAL (R10 lesson): sweep loops stay at #pragma unroll 2 -- full
// unroll hoists all 18 uint4 loads, blows past 128 VGPRs, and spills
// (R10: VGPR=128, 6.9 GB spill-writes, 5x slowdown).
#define WPB   8
#define ROWS  (N / WPB)      // 128 rows per WG
#define T     512            // 8 waves
#define NW    8
#define RL    7              // LDS rows per wave  (56 per WG)
#define RS    9              // streamed rows per wave (72 per WG)
#define SROWS (NW * RS)

// ws: counters + double-buffered partials [2][BS][WPB][M] + streamed cq
#define CNT_BYTES  4096
#define PART_OFF   ((size_t)CNT_BYTES)
#define PART_BYTES ((size_t)2 * BS * WPB * M * 4)          // 2 MB
#define CQ_OFF     (PART_OFF + PART_BYTES)
#define CQ_BYTES   ((size_t)BS * WPB * SROWS * M * 2)      // 36 MB
#define WS_NEEDED  (CQ_OFF + CQ_BYTES)

// unpack two u16 from a 32-bit word to floats (raw, unscaled)
__device__ __forceinline__ float2 upair(unsigned w) {
    return make_float2((float)(w & 0xffffu), (float)(w >> 16));
}

// Ghat = round(65535 * exp(-10*C)); the 1/65535 scales cancel algebraically:
//   u' = MU/(Ghat.v) == u/65535 ; col = sum u'*Ghat == u^T G ;
//   Gamma*n = u' * Ghat * v * N
__device__ __forceinline__ unsigned qq(float c0, float c1) {
    const float KE = -14.4269504088896340f;   // -10*log2(e)
    unsigned a = __float2uint_rn(65535.0f * __builtin_amdgcn_exp2f(KE * c0));
    unsigned b = __float2uint_rn(65535.0f * __builtin_amdgcn_exp2f(KE * c1));
    return a | (b << 16);
}

// Permuted layout per row (128 uint4 slots): slot h*64+l holds cols
// {512h+4l..+3} and {512h+256+4l..+3} -> all accesses contiguous per lane.
__global__ __launch_bounds__(T) void sinkhorn_q16d(
    const float* __restrict__ C,
    float* __restrict__ Gout,            // d_out: final Gamma*n only
    unsigned* __restrict__ cnt,          // [BS] stride-32 uints
    float* __restrict__ partials,        // [2][BS][WPB][M]
    unsigned short* __restrict__ cq)     // [BS*WPB][SROWS][M] u16 permuted
{
    const int bid  = blockIdx.x;
    const int b    = bid & (BS - 1);   // all 8 WGs of a batch: bid%8 == b%8
    const int k    = bid >> 5;         // 0..7  (co-located per XCD model)
    const int tid  = threadIdx.x;
    const int lane = tid & 63;
    const int wave = tid >> 6;

    const size_t sl = ((size_t)b * N + (size_t)k * ROWS) * M;
    const float MU = 1.0f / (float)N;
    const float NU = 1.0f / (float)M;

    // LDS: 114688 (G, 56 rows) + 32768 (part) + 4096 (v) + 512 (u) = 148.5 KB
    __shared__ uint4 Glds[NW * RL][M / 8];
    __shared__ float part[NW][M];
    __shared__ float v_lds[M];
    __shared__ float u_lds[ROWS];

    uint4* cq4 = (uint4*)cq + (size_t)(b * WPB + k) * SROWS * (M / 8);

    // ---- prologue: quantize own 128 rows (56 -> LDS, 72 -> cq) ----
    #pragma unroll 2
    for (int rr = 0; rr < 16; ++rr) {
        const int row = wave * 16 + rr;
        const float4* cr = (const float4*)(C + sl + (size_t)row * M);
        float4 a0 = cr[lane],       a1 = cr[64 + lane];
        float4 b0 = cr[128 + lane], b1 = cr[192 + lane];
        uint4 oa, ob;
        oa.x = qq(a0.x, a0.y);  oa.y = qq(a0.z, a0.w);
        oa.z = qq(a1.x, a1.y);  oa.w = qq(a1.z, a1.w);
        ob.x = qq(b0.x, b0.y);  ob.y = qq(b0.z, b0.w);
        ob.z = qq(b1.x, b1.y);  ob.w = qq(b1.z, b1.w);
        if (rr < RL) {
            Glds[wave * RL + rr][lane]      = oa;
            Glds[wave * RL + rr][64 + lane] = ob;
        } else {
            cq4[(size_t)(wave * RS + (rr - RL)) * 128 + lane]      = oa;
            cq4[(size_t)(wave * RS + (rr - RL)) * 128 + 64 + lane] = ob;
        }
    }
    ((float2*)v_lds)[tid] = make_float2(NU, NU);
    __syncthreads();

    unsigned* mycnt = cnt + b * 32;
    const float4* v4 = (const float4*)v_lds;
    float4 vra0 = v4[lane],       vra1 = v4[64 + lane],
           vrb0 = v4[128 + lane], vrb1 = v4[192 + lane];

    for (int t = 0; t < ITERS; ++t) {
        const int par = t & 1;
        float4 ca0 = make_float4(0,0,0,0), ca1 = make_float4(0,0,0,0),
               cb0 = make_float4(0,0,0,0), cb1 = make_float4(0,0,0,0);

        auto dorow = [&](uint4 qa, uint4 qb, int row) {
            float2 g0 = upair(qa.x), g1 = upair(qa.y),
                   g2 = upair(qa.z), g3 = upair(qa.w);
            float2 h0 = upair(qb.x), h1 = upair(qb.y),
                   h2 = upair(qb.z), h3 = upair(qb.w);
            float pa = (g0.x*vra0.x + g0.y*vra0.y) + (g1.x*vra0.z + g1.y*vra0.w);
            float pb = (g2.x*vra1.x + g2.y*vra1.y) + (g3.x*vra1.z + g3.y*vra1.w);
            float pc = (h0.x*vrb0.x + h0.y*vrb0.y) + (h1.x*vrb0.z + h1.y*vrb0.w);
            float pd = (h2.x*vrb1.x + h2.y*vrb1.y) + (h3.x*vrb1.z + h3.y*vrb1.w);
            float dot = (pa + pb) + (pc + pd);
            #pragma unroll
            for (int off = 32; off > 0; off >>= 1)
                dot += __shfl_xor(dot, off, 64);
            const float ui = MU / dot;
            if (lane == 0) u_lds[row] = ui;
            ca0.x += ui*g0.x; ca0.y += ui*g0.y; ca0.z += ui*g1.x; ca0.w += ui*g1.y;
            ca1.x += ui*g2.x; ca1.y += ui*g2.y; ca1.z += ui*g3.x; ca1.w += ui*g3.y;
            cb0.x += ui*h0.x; cb0.y += ui*h0.y; cb0.z += ui*h1.x; cb0.w += ui*h1.y;
            cb1.x += ui*h2.x; cb1.y += ui*h2.y; cb1.z += ui*h3.x; cb1.w += ui*h3.y;
        };

        // ---- fused sweep: 9 streamed rows then 7 LDS rows per wave ----
        // (#pragma unroll 2, NOT full unroll -- see header comment)
        #pragma unroll 2
        for (int i = 0; i < RS; ++i) {
            uint4 sa = cq4[(size_t)(wave * RS + i) * 128 + lane];
            uint4 sb = cq4[(size_t)(wave * RS + i) * 128 + 64 + lane];
            dorow(sa, sb, wave * 16 + RL + i);
        }
        #pragma unroll 2
        for (int j = 0; j < RL; ++j) {
            uint4 la = Glds[wave * RL + j][lane];
            uint4 lb = Glds[wave * RL + j][64 + lane];
            dorow(la, lb, wave * 16 + j);
        }

        // ---- combine 8 waves (R4 structure, unchanged) ----
        {
            float4* pw = (float4*)part[wave];
            pw[lane]       = ca0;
            pw[64 + lane]  = ca1;
            pw[128 + lane] = cb0;
            pw[192 + lane] = cb1;
        }
        __syncthreads();
        {
            float2 s = make_float2(0.0f, 0.0f);
            #pragma unroll
            for (int w = 0; w < NW; ++w) {
                float2 q = ((const float2*)part[w])[tid];
                s.x += q.x; s.y += q.y;
            }
            float2* pg = (float2*)(partials +
                (((size_t)par * BS + b) * WPB + k) * M);
            pg[tid] = s;
        }
        __syncthreads();
        // ---- single 8-wide inter-WG barrier for this batch ----
        if (tid == 0) {
            __hip_atomic_fetch_add(mycnt, 1u, __ATOMIC_RELEASE,
                                   __HIP_MEMORY_SCOPE_AGENT);
            const unsigned tgt = (unsigned)WPB * (unsigned)(t + 1);
            while (__hip_atomic_load(mycnt, __ATOMIC_ACQUIRE,
                                     __HIP_MEMORY_SCOPE_AGENT) < tgt)
                __builtin_amdgcn_s_sleep(1);
        }
        __syncthreads();
        // ---- v = NU / sum_p partial[p]  (fixed order, all threads) ----
        {
            const float2* pall = (const float2*)(partials +
                ((size_t)par * BS + b) * ((size_t)WPB * M));
            float2 s = pall[tid];
            #pragma unroll
            for (int p = 1; p < WPB; ++p) {
                float2 q = pall[(size_t)p * (M / 2) + tid];
                s.x += q.x; s.y += q.y;
            }
            ((float2*)v_lds)[tid] = make_float2(NU / s.x, NU / s.y);
        }
        __syncthreads();
        vra0 = v4[lane];       vra1 = v4[64 + lane];
        vrb0 = v4[128 + lane]; vrb1 = v4[192 + lane];
    }

    // ---- epilogue: Gamma*n = u' * Ghat * v * N (scales cancel) ----
    const float nN = (float)N;
    auto emit = [&](float* rowp, uint4 qa, uint4 qb, float un) {
        float2 g0 = upair(qa.x), g1 = upair(qa.y),
               g2 = upair(qa.z), g3 = upair(qa.w);
        float2 h0 = upair(qb.x), h1 = upair(qb.y),
               h2 = upair(qb.z), h3 = upair(qb.w);
        float4* o4 = (float4*)rowp;
        o4[lane]       = make_float4(un*g0.x*vra0.x, un*g0.y*vra0.y,
                                     un*g1.x*vra0.z, un*g1.y*vra0.w);
        o4[64 + lane]  = make_float4(un*g2.x*vra1.x, un*g2.y*vra1.y,
                                     un*g3.x*vra1.z, un*g3.y*vra1.w);
        o4[128 + lane] = make_float4(un*h0.x*vrb0.x, un*h0.y*vrb0.y,
                                     un*h1.x*vrb0.z, un*h1.y*vrb0.w);
        o4[192 + lane] = make_float4(un*h2.x*vrb1.x, un*h2.y*vrb1.y,
                                     un*h3.x*vrb1.z, un*h3.y*vrb1.w);
    };
    #pragma unroll 2
    for (int i = 0; i < RS; ++i) {
        const int row = wave * 16 + RL + i;
        uint4 sa = cq4[(size_t)(wave * RS + i) * 128 + lane];
        uint4 sb = cq4[(size_t)(wave * RS + i) * 128 + 64 + lane];
        emit(Gout + sl + (size_t)row * M, sa, sb, u_lds[row] * nN);
    }
    #pragma unroll 2
    for (int j = 0; j < RL; ++j) {
        const int row = wave * 16 + j;
        uint4 la = Glds[wave * RL + j][lane];
        uint4 lb = Glds[wave * RL + j][64 + lane];
        emit(Gout + sl + (size_t)row * M, la, lb, u_lds[row] * nN);
    }
}

extern "C" void kernel_launch(void* const* d_in, const int* in_sizes, int n_in,
                              void* d_out, int out_size, void* d_ws, size_t ws_size,
                              hipStream_t stream) {
    (void)in_sizes; (void)n_in; (void)out_size;

    const float* C = (const float*)d_in[0];
    float* Gout = (float*)d_out;
    char* ws = (char*)d_ws;

    if (ws_size < WS_NEEDED) return;   // fail loudly (output stays poisoned)

    // Re-zero barrier counters every launch (graph-replay safe).
    hipMemsetAsync(d_ws, 0, CNT_BYTES, stream);

    unsigned* cnt      = (unsigned*)ws;
    float* partials    = (float*)(ws + PART_OFF);
    unsigned short* cq = (unsigned short*)(ws + CQ_OFF);
    sinkhorn_q16d<<<dim3(BS * WPB), dim3(T), 0, stream>>>(
        C, Gout, cnt, partials, cq);
}

// Round 12
// 3570.181 us; speedup vs baseline: 1.8718x; 1.8718x over previous
//
#include <hip/hip_runtime.h>
#include <math.h>

// Problem constants (reference: BS=32, N=M=1024, eps=0.1, 200 iters)
#define BS    32
#define N     1024
#define M     1024
#define ITERS 200

// R4's proven minimal skeleton (8 WGs/batch, 512 thr, grid 256 = 1 WG/CU,
// 3 intra-WG syncs, one 8-wide atomic barrier, flat 8-way v-reduce).
// Residency split: 56 rows/WG in LDS u16 (112 KB), 72 rows streamed from cq
// (144 KB/WG/iter, -44% vs R4).
// SPILL CONTROL (R9/R10/R11 lesson): mixing streamed-global rows and LDS rows
// lets the scheduler hoist ALL their loads into one in-flight set -> >128
// VGPRs -> scratch spill (35 MB/iter). Fences:
//   - streamed loop in 3 chunks of 3 rows, sched_barrier(0) between chunks
//     (caps in-flight global loads at 3 rows/wave = enough MLP, no more);
//   - sched_barrier(0) between streamed loop and LDS loop (stops ds_read
//     hoisting / global sinking across the boundary).
#define WPB   8
#define ROWS  (N / WPB)      // 128 rows per WG
#define T     512            // 8 waves
#define NW    8
#define RL    7              // LDS rows per wave  (56 per WG)
#define RS    9              // streamed rows per wave (72 per WG)
#define SROWS (NW * RS)

// ws: counters + double-buffered partials [2][BS][WPB][M] + streamed cq
#define CNT_BYTES  4096
#define PART_OFF   ((size_t)CNT_BYTES)
#define PART_BYTES ((size_t)2 * BS * WPB * M * 4)          // 2 MB
#define CQ_OFF     (PART_OFF + PART_BYTES)
#define CQ_BYTES   ((size_t)BS * WPB * SROWS * M * 2)      // 36 MB
#define WS_NEEDED  (CQ_OFF + CQ_BYTES)

// unpack two u16 from a 32-bit word to floats (raw, unscaled)
__device__ __forceinline__ float2 upair(unsigned w) {
    return make_float2((float)(w & 0xffffu), (float)(w >> 16));
}

// Ghat = round(65535 * exp(-10*C)); the 1/65535 scales cancel algebraically:
//   u' = MU/(Ghat.v) == u/65535 ; col = sum u'*Ghat == u^T G ;
//   Gamma*n = u' * Ghat * v * N
__device__ __forceinline__ unsigned qq(float c0, float c1) {
    const float KE = -14.4269504088896340f;   // -10*log2(e)
    unsigned a = __float2uint_rn(65535.0f * __builtin_amdgcn_exp2f(KE * c0));
    unsigned b = __float2uint_rn(65535.0f * __builtin_amdgcn_exp2f(KE * c1));
    return a | (b << 16);
}

// row body as MACRO (R7's no-spill pattern; no lambda)
#define DOROW(QA_, QB_, ROW_) do {                                            \
    float2 g0_ = upair((QA_).x), g1_ = upair((QA_).y),                        \
           g2_ = upair((QA_).z), g3_ = upair((QA_).w);                        \
    float2 h0_ = upair((QB_).x), h1_ = upair((QB_).y),                        \
           h2_ = upair((QB_).z), h3_ = upair((QB_).w);                        \
    float pa_ = (g0_.x*vra0.x + g0_.y*vra0.y) + (g1_.x*vra0.z + g1_.y*vra0.w);\
    float pb_ = (g2_.x*vra1.x + g2_.y*vra1.y) + (g3_.x*vra1.z + g3_.y*vra1.w);\
    float pc_ = (h0_.x*vrb0.x + h0_.y*vrb0.y) + (h1_.x*vrb0.z + h1_.y*vrb0.w);\
    float pd_ = (h2_.x*vrb1.x + h2_.y*vrb1.y) + (h3_.x*vrb1.z + h3_.y*vrb1.w);\
    float dot_ = (pa_ + pb_) + (pc_ + pd_);                                   \
    _Pragma("unroll")                                                         \
    for (int o_ = 32; o_ > 0; o_ >>= 1) dot_ += __shfl_xor(dot_, o_, 64);     \
    const float ui_ = MU / dot_;                                              \
    if (lane == 0) u_lds[ROW_] = ui_;                                         \
    ca0.x += ui_*g0_.x; ca0.y += ui_*g0_.y; ca0.z += ui_*g1_.x; ca0.w += ui_*g1_.y; \
    ca1.x += ui_*g2_.x; ca1.y += ui_*g2_.y; ca1.z += ui_*g3_.x; ca1.w += ui_*g3_.y; \
    cb0.x += ui_*h0_.x; cb0.y += ui_*h0_.y; cb0.z += ui_*h1_.x; cb0.w += ui_*h1_.y; \
    cb1.x += ui_*h2_.x; cb1.y += ui_*h2_.y; cb1.z += ui_*h3_.x; cb1.w += ui_*h3_.y; \
} while (0)

// Permuted layout per row (128 uint4 slots): slot h*64+l holds cols
// {512h+4l..+3} and {512h+256+4l..+3} -> all accesses contiguous per lane.
__global__ __launch_bounds__(T) void sinkhorn_q16e(
    const float* __restrict__ C,
    float* __restrict__ Gout,            // d_out: final Gamma*n only
    unsigned* __restrict__ cnt,          // [BS] stride-32 uints
    float* __restrict__ partials,        // [2][BS][WPB][M]
    unsigned short* __restrict__ cq)     // [BS*WPB][SROWS][M] u16 permuted
{
    const int bid  = blockIdx.x;
    const int b    = bid & (BS - 1);   // all 8 WGs of a batch: bid%8 == b%8
    const int k    = bid >> 5;         // 0..7  (co-located per XCD model)
    const int tid  = threadIdx.x;
    const int lane = tid & 63;
    const int wave = tid >> 6;

    const size_t sl = ((size_t)b * N + (size_t)k * ROWS) * M;
    const float MU = 1.0f / (float)N;
    const float NU = 1.0f / (float)M;

    // LDS: 114688 (G, 56 rows) + 32768 (part) + 4096 (v) + 512 (u) = 148.5 KB
    __shared__ uint4 Glds[NW * RL][M / 8];
    __shared__ float part[NW][M];
    __shared__ float v_lds[M];
    __shared__ float u_lds[ROWS];

    uint4* cq4 = (uint4*)cq + (size_t)(b * WPB + k) * SROWS * (M / 8);

    // ---- prologue: quantize own 128 rows (56 -> LDS, 72 -> cq) ----
    #pragma unroll 2
    for (int rr = 0; rr < 16; ++rr) {
        const int row = wave * 16 + rr;
        const float4* cr = (const float4*)(C + sl + (size_t)row * M);
        float4 a0 = cr[lane],       a1 = cr[64 + lane];
        float4 b0 = cr[128 + lane], b1 = cr[192 + lane];
        uint4 oa, ob;
        oa.x = qq(a0.x, a0.y);  oa.y = qq(a0.z, a0.w);
        oa.z = qq(a1.x, a1.y);  oa.w = qq(a1.z, a1.w);
        ob.x = qq(b0.x, b0.y);  ob.y = qq(b0.z, b0.w);
        ob.z = qq(b1.x, b1.y);  ob.w = qq(b1.z, b1.w);
        if (rr < RL) {
            Glds[wave * RL + rr][lane]      = oa;
            Glds[wave * RL + rr][64 + lane] = ob;
        } else {
            cq4[(size_t)(wave * RS + (rr - RL)) * 128 + lane]      = oa;
            cq4[(size_t)(wave * RS + (rr - RL)) * 128 + 64 + lane] = ob;
        }
    }
    ((float2*)v_lds)[tid] = make_float2(NU, NU);
    __syncthreads();

    unsigned* mycnt = cnt + b * 32;
    const float4* v4 = (const float4*)v_lds;
    float4 vra0 = v4[lane],       vra1 = v4[64 + lane],
           vrb0 = v4[128 + lane], vrb1 = v4[192 + lane];

    for (int t = 0; t < ITERS; ++t) {
        const int par = t & 1;
        float4 ca0 = make_float4(0,0,0,0), ca1 = make_float4(0,0,0,0),
               cb0 = make_float4(0,0,0,0), cb1 = make_float4(0,0,0,0);

        // ---- streamed rows: 3 chunks of 3, fenced (caps in-flight loads) --
        #pragma unroll 1
        for (int c = 0; c < 3; ++c) {
            #pragma unroll
            for (int i = 0; i < 3; ++i) {
                const int r = c * 3 + i;
                uint4 sa = cq4[(size_t)(wave * RS + r) * 128 + lane];
                uint4 sb = cq4[(size_t)(wave * RS + r) * 128 + 64 + lane];
                DOROW(sa, sb, wave * 16 + RL + r);
            }
            __builtin_amdgcn_sched_barrier(0);
        }
        __builtin_amdgcn_sched_barrier(0);
        // ---- LDS rows: 7, unroll 2 (ds_read latency is short) ----
        #pragma unroll 2
        for (int j = 0; j < RL; ++j) {
            uint4 la = Glds[wave * RL + j][lane];
            uint4 lb = Glds[wave * RL + j][64 + lane];
            DOROW(la, lb, wave * 16 + j);
        }

        // ---- combine 8 waves (R4 structure, unchanged) ----
        {
            float4* pw = (float4*)part[wave];
            pw[lane]       = ca0;
            pw[64 + lane]  = ca1;
            pw[128 + lane] = cb0;
            pw[192 + lane] = cb1;
        }
        __syncthreads();
        {
            float2 s = make_float2(0.0f, 0.0f);
            #pragma unroll
            for (int w = 0; w < NW; ++w) {
                float2 q = ((const float2*)part[w])[tid];
                s.x += q.x; s.y += q.y;
            }
            float2* pg = (float2*)(partials +
                (((size_t)par * BS + b) * WPB + k) * M);
            pg[tid] = s;
        }
        __syncthreads();
        // ---- single 8-wide inter-WG barrier for this batch ----
        if (tid == 0) {
            __hip_atomic_fetch_add(mycnt, 1u, __ATOMIC_RELEASE,
                                   __HIP_MEMORY_SCOPE_AGENT);
            const unsigned tgt = (unsigned)WPB * (unsigned)(t + 1);
            while (__hip_atomic_load(mycnt, __ATOMIC_ACQUIRE,
                                     __HIP_MEMORY_SCOPE_AGENT) < tgt)
                __builtin_amdgcn_s_sleep(1);
        }
        __syncthreads();
        // ---- v = NU / sum_p partial[p]  (fixed order, all threads) ----
        {
            const float2* pall = (const float2*)(partials +
                ((size_t)par * BS + b) * ((size_t)WPB * M));
            float2 s = pall[tid];
            #pragma unroll
            for (int p = 1; p < WPB; ++p) {
                float2 q = pall[(size_t)p * (M / 2) + tid];
                s.x += q.x; s.y += q.y;
            }
            ((float2*)v_lds)[tid] = make_float2(NU / s.x, NU / s.y);
        }
        __syncthreads();
        vra0 = v4[lane];       vra1 = v4[64 + lane];
        vrb0 = v4[128 + lane]; vrb1 = v4[192 + lane];
    }

    // ---- epilogue: Gamma*n = u' * Ghat * v * N (scales cancel) ----
    const float nN = (float)N;
    auto emit = [&](float* rowp, uint4 qa, uint4 qb, float un) {
        float2 g0 = upair(qa.x), g1 = upair(qa.y),
               g2 = upair(qa.z), g3 = upair(qa.w);
        float2 h0 = upair(qb.x), h1 = upair(qb.y),
               h2 = upair(qb.z), h3 = upair(qb.w);
        float4* o4 = (float4*)rowp;
        o4[lane]       = make_float4(un*g0.x*vra0.x, un*g0.y*vra0.y,
                                     un*g1.x*vra0.z, un*g1.y*vra0.w);
        o4[64 + lane]  = make_float4(un*g2.x*vra1.x, un*g2.y*vra1.y,
                                     un*g3.x*vra1.z, un*g3.y*vra1.w);
        o4[128 + lane] = make_float4(un*h0.x*vrb0.x, un*h0.y*vrb0.y,
                                     un*h1.x*vrb0.z, un*h1.y*vrb0.w);
        o4[192 + lane] = make_float4(un*h2.x*vrb1.x, un*h2.y*vrb1.y,
                                     un*h3.x*vrb1.z, un*h3.y*vrb1.w);
    };
    #pragma unroll 2
    for (int i = 0; i < RS; ++i) {
        const int row = wave * 16 + RL + i;
        uint4 sa = cq4[(size_t)(wave * RS + i) * 128 + lane];
        uint4 sb = cq4[(size_t)(wave * RS + i) * 128 + 64 + lane];
        emit(Gout + sl + (size_t)row * M, sa, sb, u_lds[row] * nN);
    }
    #pragma unroll 2
    for (int j = 0; j < RL; ++j) {
        const int row = wave * 16 + j;
        uint4 la = Glds[wave * RL + j][lane];
        uint4 lb = Glds[wave * RL + j][64 + lane];
        emit(Gout + sl + (size_t)row * M, la, lb, u_lds[row] * nN);
    }
}

extern "C" void kernel_launch(void* const* d_in, const int* in_sizes, int n_in,
                              void* d_out, int out_size, void* d_ws, size_t ws_size,
                              hipStream_t stream) {
    (void)in_sizes; (void)n_in; (void)out_size;

    const float* C = (const float*)d_in[0];
    float* Gout = (float*)d_out;
    char* ws = (char*)d_ws;

    if (ws_size < WS_NEEDED) return;   // fail loudly (output stays poisoned)

    // Re-zero barrier counters every launch (graph-replay safe).
    hipMemsetAsync(d_ws, 0, CNT_BYTES, stream);

    unsigned* cnt      = (unsigned*)ws;
    float* partials    = (float*)(ws + PART_OFF);
    unsigned short* cq = (unsigned short*)(ws + CQ_OFF);
    sinkhorn_q16e<<<dim3(BS * WPB), dim3(T), 0, stream>>>(
        C, Gout, cnt, partials, cq);
}